// Round 2
// baseline (11161.266 us; speedup 1.0000x reference)
//
#include <hip/hip_runtime.h>
#include <hip/hip_bf16.h>

// Problem: B=4, T=2048, E=1024, H=16, HD=64.
// Inputs/outputs are fp32 (reference dtypes); comparison is bf16-tolerance,
// so intermediates (q,k,v,att) are stored bf16 in d_ws (67 MB).
#define B_  4
#define T_  2048
#define E_  1024
#define H_  16
#define HD_ 64

typedef __hip_bfloat16 bf16;

__device__ __forceinline__ float b2f(bf16 x) { return __bfloat162float(x); }
__device__ __forceinline__ bf16  f2b(float x) { return __float2bfloat16(x); }

// ---------------------------------------------------------------------------
// Kernel 1: fused QKV projection.
// C[m,n] = sum_k X[m,k] * W[h, k, d]   with n = h*64 + d, m = b*T + t.
// BN=64 == HD, so each n-tile is exactly one head -> coalesced W loads.
// Output layout: q/k/v [B, H, T, HD] (bf16).
// ---------------------------------------------------------------------------
__global__ __launch_bounds__(256) void qkv_gemm(
    const float* __restrict__ x,
    const float* __restrict__ Wq, const float* __restrict__ Wk, const float* __restrict__ Wv,
    bf16* __restrict__ q, bf16* __restrict__ k, bf16* __restrict__ v)
{
    const float* W; bf16* out;
    switch (blockIdx.z) {
        case 0:  W = Wq; out = q; break;
        case 1:  W = Wk; out = k; break;
        default: W = Wv; out = v; break;
    }
    const int m0 = blockIdx.x * 64;
    const int n0 = blockIdx.y * 64;
    const int h  = n0 >> 6;

    __shared__ float As[16][64 + 1];  // [k][m]
    __shared__ float Bs[16][64 + 1];  // [k][n]

    const int tid = threadIdx.x;
    const int tx = tid & 15, ty = tid >> 4;
    float acc[4][4] = {};

    for (int k0 = 0; k0 < E_; k0 += 16) {
        {   // A tile: 64 rows x 16 k, float4 per thread
            int row = tid >> 2, kk = (tid & 3) << 2;
            float4 a4 = *(const float4*)(x + (size_t)(m0 + row) * E_ + k0 + kk);
            As[kk + 0][row] = a4.x; As[kk + 1][row] = a4.y;
            As[kk + 2][row] = a4.z; As[kk + 3][row] = a4.w;
        }
        {   // B tile: W[h][k0+kr][d], d coalesced across the wave
            int d = tid & 63, kb = tid >> 6;
            const float* p = W + (size_t)h * E_ * HD_ + (size_t)(k0 + kb) * HD_ + d;
            #pragma unroll
            for (int i = 0; i < 4; i++) Bs[kb + 4 * i][d] = p[(size_t)(4 * i) * HD_];
        }
        __syncthreads();
        #pragma unroll
        for (int kk = 0; kk < 16; kk++) {
            float a[4], b[4];
            #pragma unroll
            for (int i = 0; i < 4; i++) a[i] = As[kk][ty * 4 + i];
            #pragma unroll
            for (int j = 0; j < 4; j++) b[j] = Bs[kk][tx * 4 + j];
            #pragma unroll
            for (int i = 0; i < 4; i++)
                #pragma unroll
                for (int j = 0; j < 4; j++) acc[i][j] += a[i] * b[j];
        }
        __syncthreads();
    }
    #pragma unroll
    for (int i = 0; i < 4; i++) {
        int m = m0 + ty * 4 + i;
        int bb = m / T_, t = m % T_;
        #pragma unroll
        for (int j = 0; j < 4; j++) {
            int d = tx * 4 + j;
            out[(((size_t)(bb * H_ + h) * T_ + t) * HD_) + d] = f2b(acc[i][j]);
        }
    }
}

// ---------------------------------------------------------------------------
// Kernel 2: causal attention, one block (256 thr = 4 waves) per (b,h,tq) row.
// Phase 1: wave w computes scores s = w, w+4, ... via 64-lane shuffle-reduce.
// Softmax over the full score row held in LDS (T=2048 floats = 8 KB).
// Phase 2: lane = d, wave-strided over s; partial sums reduced through LDS.
// att output layout: [B, T, H, HD] (so the out-proj GEMM sees row-major A).
// ---------------------------------------------------------------------------
__global__ __launch_bounds__(256) void attn(
    const bf16* __restrict__ q, const bf16* __restrict__ k,
    const bf16* __restrict__ v, bf16* __restrict__ att)
{
    const int idx = blockIdx.x;       // b*H*T + h*T + tq
    const int tq  = idx % T_;
    const int bh  = idx / T_;
    const int hh  = bh % H_;
    const int bb  = bh / H_;
    const int tid = threadIdx.x;
    const int lane = tid & 63, wave = tid >> 6;

    __shared__ float qs[HD_];
    __shared__ float ps[T_];
    __shared__ float red[4];
    __shared__ float part[4][HD_];

    const size_t base = (size_t)bh * T_ * HD_;
    if (tid < HD_) qs[tid] = b2f(q[base + (size_t)tq * HD_ + tid]) * 0.125f; // 1/sqrt(64)
    __syncthreads();

    const int nS = tq + 1;
    const float qv = qs[lane];

    // Phase 1: scores
    for (int s = wave; s < nS; s += 4) {
        float val = qv * b2f(k[base + (size_t)s * HD_ + lane]);
        #pragma unroll
        for (int off = 32; off > 0; off >>= 1) val += __shfl_xor(val, off, 64);
        if (lane == 0) ps[s] = val;
    }
    __syncthreads();

    // Softmax: block max
    float lm = -INFINITY;
    for (int s = tid; s < nS; s += 256) lm = fmaxf(lm, ps[s]);
    #pragma unroll
    for (int off = 32; off > 0; off >>= 1) lm = fmaxf(lm, __shfl_xor(lm, off, 64));
    if (lane == 0) red[wave] = lm;
    __syncthreads();
    const float m = fmaxf(fmaxf(red[0], red[1]), fmaxf(red[2], red[3]));

    // exp + sum
    float lsum = 0.f;
    for (int s = tid; s < nS; s += 256) { float e = __expf(ps[s] - m); ps[s] = e; lsum += e; }
    #pragma unroll
    for (int off = 32; off > 0; off >>= 1) lsum += __shfl_xor(lsum, off, 64);
    __syncthreads();                    // exp writes done; red[] free to reuse
    if (lane == 0) red[wave] = lsum;
    __syncthreads();
    const float inv_l = 1.f / (red[0] + red[1] + red[2] + red[3]);

    // Phase 2: out[d] = sum_s p[s] * v[s,d]
    float acc = 0.f;
    for (int s = wave; s < nS; s += 4)
        acc += ps[s] * b2f(v[base + (size_t)s * HD_ + lane]);
    part[wave][lane] = acc;
    __syncthreads();
    if (tid < HD_) {
        float o = (part[0][tid] + part[1][tid] + part[2][tid] + part[3][tid]) * inv_l;
        att[(((size_t)bb * T_ + tq) * H_ + hh) * HD_ + tid] = f2b(o);
    }
}

// ---------------------------------------------------------------------------
// Kernel 3: output projection: out[m,n] = sum_f att[m,f] * Wo[n,f] + bo[n]
// ---------------------------------------------------------------------------
__global__ __launch_bounds__(256) void out_proj(
    const bf16* __restrict__ att, const float* __restrict__ Wo,
    const float* __restrict__ bo, float* __restrict__ out)
{
    const int m0 = blockIdx.x * 64;
    const int n0 = blockIdx.y * 64;

    __shared__ float As[16][64 + 1];
    __shared__ float Bs[16][64 + 1];

    const int tid = threadIdx.x;
    const int tx = tid & 15, ty = tid >> 4;
    float acc[4][4] = {};

    for (int k0 = 0; k0 < E_; k0 += 16) {
        {
            int row = tid >> 2, kk = (tid & 3) << 2;
            const bf16* p = att + (size_t)(m0 + row) * E_ + k0 + kk;
            #pragma unroll
            for (int i = 0; i < 4; i++) As[kk + i][row] = b2f(p[i]);
        }
        {   // B[kk][nn] = Wo[n0+nn][k0+kk]; float4 loads, transposed store
            int nn = tid >> 2, kk = (tid & 3) << 2;
            float4 b4 = *(const float4*)(Wo + (size_t)(n0 + nn) * E_ + k0 + kk);
            Bs[kk + 0][nn] = b4.x; Bs[kk + 1][nn] = b4.y;
            Bs[kk + 2][nn] = b4.z; Bs[kk + 3][nn] = b4.w;
        }
        __syncthreads();
        #pragma unroll
        for (int kk = 0; kk < 16; kk++) {
            float a[4], b[4];
            #pragma unroll
            for (int i = 0; i < 4; i++) a[i] = As[kk][ty * 4 + i];
            #pragma unroll
            for (int j = 0; j < 4; j++) b[j] = Bs[kk][tx * 4 + j];
            #pragma unroll
            for (int i = 0; i < 4; i++)
                #pragma unroll
                for (int j = 0; j < 4; j++) acc[i][j] += a[i] * b[j];
        }
        __syncthreads();
    }
    #pragma unroll
    for (int j = 0; j < 4; j++) {
        int n = n0 + tx * 4 + j;
        float bias = bo[n];
        #pragma unroll
        for (int i = 0; i < 4; i++) {
            int m = m0 + ty * 4 + i;
            out[(size_t)m * E_ + n] = acc[i][j] + bias;
        }
    }
}

// ---------------------------------------------------------------------------
extern "C" void kernel_launch(void* const* d_in, const int* in_sizes, int n_in,
                              void* d_out, int out_size, void* d_ws, size_t ws_size,
                              hipStream_t stream)
{
    const float* x  = (const float*)d_in[0];
    const float* Wq = (const float*)d_in[1];
    const float* Wk = (const float*)d_in[2];
    const float* Wv = (const float*)d_in[3];
    const float* Wo = (const float*)d_in[4];
    const float* bo = (const float*)d_in[5];
    float* out = (float*)d_out;

    const size_t elts = (size_t)B_ * H_ * T_ * HD_;   // 8,388,608
    bf16* q   = (bf16*)d_ws;          // [B,H,T,HD]
    bf16* k   = q + elts;             // [B,H,T,HD]
    bf16* v   = k + elts;             // [B,H,T,HD]
    bf16* att = v + elts;             // [B,T,H,HD]  (~67 MB total scratch)

    dim3 g_qkv(/*M/64*/ (B_ * T_) / 64, /*N/64*/ E_ / 64, 3);
    qkv_gemm<<<g_qkv, 256, 0, stream>>>(x, Wq, Wk, Wv, q, k, v);

    attn<<<dim3(B_ * H_ * T_), 256, 0, stream>>>(q, k, v, att);

    dim3 g_proj((B_ * T_) / 64, E_ / 64);
    out_proj<<<g_proj, 256, 0, stream>>>(att, Wo, bo, out);
}

// Round 3
// 1451.049 us; speedup vs baseline: 7.6919x; 7.6919x over previous
//
#include <hip/hip_runtime.h>
#include <hip/hip_bf16.h>

// B=4, T=2048, E=1024, H=16, HD=64. fp32 in/out; bf16 intermediates in d_ws.
#define B_  4
#define T_  2048
#define E_  1024
#define H_  16
#define HD_ 64

typedef __hip_bfloat16 bf16;
typedef unsigned short u16;
using bf16x8 = __attribute__((ext_vector_type(8))) short;
using f32x4  = __attribute__((ext_vector_type(4))) float;

__device__ __forceinline__ float b2f(bf16 x) { return __bfloat162float(x); }
__device__ __forceinline__ bf16  f2b(float x) { return __float2bfloat16(x); }
__device__ __forceinline__ u16 f2b_bits(float x) {
    union { bf16 h; u16 u; } cv; cv.h = __float2bfloat16(x); return cv.u;
}
__device__ __forceinline__ float bits2f(u16 u) {
    union { float f; unsigned int i; } cv; cv.i = ((unsigned int)u) << 16; return cv.f;
}

// ---------------------------------------------------------------------------
// Kernel 1: fused QKV projection. C[m,n] = sum_k X[m,k]*W[h,k,d], n=h*64+d.
// q,k stored [B,H,T,HD]; v stored TRANSPOSED [B,H,HD,T] (for flash PV frags).
// ---------------------------------------------------------------------------
__global__ __launch_bounds__(256) void qkv_gemm(
    const float* __restrict__ x,
    const float* __restrict__ Wq, const float* __restrict__ Wk, const float* __restrict__ Wv,
    bf16* __restrict__ q, bf16* __restrict__ k, bf16* __restrict__ v)
{
    const float* W; bf16* out;
    switch (blockIdx.z) {
        case 0:  W = Wq; out = q; break;
        case 1:  W = Wk; out = k; break;
        default: W = Wv; out = v; break;
    }
    const int m0 = blockIdx.x * 64;
    const int n0 = blockIdx.y * 64;
    const int h  = n0 >> 6;

    __shared__ float As[16][64 + 1];  // [k][m]
    __shared__ float Bs[16][64 + 1];  // [k][n]
    __shared__ __align__(16) u16 Ts[64][72];  // V-transpose staging

    const int tid = threadIdx.x;
    const int tx = tid & 15, ty = tid >> 4;
    float acc[4][4] = {};

    for (int k0 = 0; k0 < E_; k0 += 16) {
        {   // A tile: 64 rows x 16 k, float4 per thread
            int row = tid >> 2, kk = (tid & 3) << 2;
            float4 a4 = *(const float4*)(x + (size_t)(m0 + row) * E_ + k0 + kk);
            As[kk + 0][row] = a4.x; As[kk + 1][row] = a4.y;
            As[kk + 2][row] = a4.z; As[kk + 3][row] = a4.w;
        }
        {   // B tile: W[h][k0+kr][d], d coalesced across the wave
            int d = tid & 63, kb = tid >> 6;
            const float* p = W + (size_t)h * E_ * HD_ + (size_t)(k0 + kb) * HD_ + d;
            #pragma unroll
            for (int i = 0; i < 4; i++) Bs[kb + 4 * i][d] = p[(size_t)(4 * i) * HD_];
        }
        __syncthreads();
        #pragma unroll
        for (int kk = 0; kk < 16; kk++) {
            float a[4], b[4];
            #pragma unroll
            for (int i = 0; i < 4; i++) a[i] = As[kk][ty * 4 + i];
            #pragma unroll
            for (int j = 0; j < 4; j++) b[j] = Bs[kk][tx * 4 + j];
            #pragma unroll
            for (int i = 0; i < 4; i++)
                #pragma unroll
                for (int j = 0; j < 4; j++) acc[i][j] += a[i] * b[j];
        }
        __syncthreads();
    }

    if (blockIdx.z != 2) {
        #pragma unroll
        for (int i = 0; i < 4; i++) {
            int m = m0 + ty * 4 + i;
            int bb = m / T_, t = m % T_;
            #pragma unroll
            for (int j = 0; j < 4; j++) {
                int d = tx * 4 + j;
                out[(((size_t)(bb * H_ + h) * T_ + t) * HD_) + d] = f2b(acc[i][j]);
            }
        }
    } else {
        // transpose in LDS, store V as [B,H,HD,T] with coalesced rows
        #pragma unroll
        for (int i = 0; i < 4; i++)
            #pragma unroll
            for (int j = 0; j < 4; j++)
                Ts[tx * 4 + j][ty * 4 + i] = f2b_bits(acc[i][j]);
        __syncthreads();
        int d = tid >> 2, mc = (tid & 3) * 16;
        int bb = m0 / T_, t0 = (m0 % T_) + mc;
        bf16* dst = out + ((size_t)(bb * H_ + h) * HD_ + d) * T_ + t0;
        *(uint4*)(dst)     = *(const uint4*)&Ts[d][mc];
        *(uint4*)(dst + 8) = *(const uint4*)&Ts[d][mc + 8];
    }
}

// ---------------------------------------------------------------------------
// Kernel 2: MFMA flash attention (causal). Block = 256 thr = 4 waves.
// Block handles (b*H+h, 64-row Q-tile). Wave w owns rows [16w,16w+16).
// K-tiles of 64 iterate 0..qt (diagonal tile masked). Online softmax.
// mfma_f32_16x16x32_bf16; A-layout: A[m=lane&15][k=quad*8+j];
// B-layout: B[k=quad*8+j][n=lane&15]; C/D: col=lane&15, row=quad*4+reg.
// ---------------------------------------------------------------------------
__global__ __launch_bounds__(256) void flash_attn(
    const bf16* __restrict__ q, const bf16* __restrict__ k,
    const bf16* __restrict__ vt, bf16* __restrict__ att)
{
    const int bh = blockIdx.x & 63;          // b*H + h
    const int qt = 31 - (blockIdx.x >> 6);   // heavy q-tiles dispatch first
    const int q0 = qt * 64;
    const int hh = bh & 15, bb = bh >> 4;
    const int tid = threadIdx.x, lane = tid & 63, wave = tid >> 6;
    const int quad = lane >> 4, l15 = lane & 15;

    __shared__ __align__(16) u16 Ks[64][72];       // K[s][d], pad->2-way max
    __shared__ __align__(16) u16 Vs[64][72];       // V^T: Vs[d][s]
    __shared__ __align__(16) u16 Ps[4][16][72];    // per-wave P strip

    const size_t baseK = (size_t)bh * T_ * HD_;
    const bf16* vbase = vt + (size_t)bh * (size_t)HD_ * T_;

    // Q fragments (A-layout), scaled by 1/sqrt(HD)=0.125 (exact: pow2)
    bf16x8 qfrag[2];
    {
        const bf16* qrow = q + baseK + (size_t)(q0 + wave * 16 + l15) * HD_;
        #pragma unroll
        for (int ks = 0; ks < 2; ks++)
            #pragma unroll
            for (int j = 0; j < 8; j++)
                ((short*)&qfrag[ks])[j] =
                    (short)f2b_bits(b2f(qrow[ks * 32 + quad * 8 + j]) * 0.125f);
    }

    f32x4 o[4];
    #pragma unroll
    for (int ct = 0; ct < 4; ct++) o[ct] = f32x4{0.f, 0.f, 0.f, 0.f};
    float m_i[4], l_i[4];
    #pragma unroll
    for (int r = 0; r < 4; r++) { m_i[r] = -1e30f; l_i[r] = 0.f; }

    for (int st = 0; st <= qt; st++) {
        const int s0 = st * 64;
        __syncthreads();   // previous iteration's LDS reads done
        {   // stage K tile + V^T tile: 16B per thread per row-pass
            int r = tid >> 3, c = (tid & 7) * 8;
            *(uint4*)&Ks[r][c]      = *(const uint4*)(k + baseK + (size_t)(s0 + r) * HD_ + c);
            *(uint4*)&Ks[r + 32][c] = *(const uint4*)(k + baseK + (size_t)(s0 + r + 32) * HD_ + c);
            *(uint4*)&Vs[r][c]      = *(const uint4*)(vbase + (size_t)r * T_ + s0 + c);
            *(uint4*)&Vs[r + 32][c] = *(const uint4*)(vbase + (size_t)(r + 32) * T_ + s0 + c);
        }
        __syncthreads();

        // S = Q·K^T : 4 col-tiles of 16, K=64 in 2 mfma steps
        f32x4 s[4];
        #pragma unroll
        for (int ct = 0; ct < 4; ct++) {
            f32x4 acc = f32x4{0.f, 0.f, 0.f, 0.f};
            #pragma unroll
            for (int ks = 0; ks < 2; ks++) {
                bf16x8 bfrag = *(const bf16x8*)&Ks[ct * 16 + l15][ks * 32 + quad * 8];
                acc = __builtin_amdgcn_mfma_f32_16x16x32_bf16(qfrag[ks], bfrag, acc, 0, 0, 0);
            }
            s[ct] = acc;
        }

        if (st == qt) {   // diagonal tile: mask s > q
            #pragma unroll
            for (int ct = 0; ct < 4; ct++) {
                int sg = ct * 16 + l15;
                #pragma unroll
                for (int r = 0; r < 4; r++) {
                    int qg = wave * 16 + quad * 4 + r;
                    if (sg > qg) s[ct][r] = -1e30f;
                }
            }
        }

        // online softmax: row max over tile (16 lanes x 4 col-tiles)
        float alpha[4];
        #pragma unroll
        for (int r = 0; r < 4; r++) {
            float v = fmaxf(fmaxf(s[0][r], s[1][r]), fmaxf(s[2][r], s[3][r]));
            #pragma unroll
            for (int off = 8; off >= 1; off >>= 1) v = fmaxf(v, __shfl_xor(v, off, 64));
            float mn = fmaxf(m_i[r], v);
            alpha[r] = __expf(m_i[r] - mn);
            m_i[r] = mn;
        }

        // P = exp(S - m) rounded to bf16; row sums use rounded values
        float rsum[4] = {0.f, 0.f, 0.f, 0.f};
        #pragma unroll
        for (int ct = 0; ct < 4; ct++) {
            #pragma unroll
            for (int r = 0; r < 4; r++) {
                float p = __expf(s[ct][r] - m_i[r]);
                u16 pb = f2b_bits(p);
                rsum[r] += bits2f(pb);
                Ps[wave][quad * 4 + r][ct * 16 + l15] = pb;
            }
        }
        #pragma unroll
        for (int r = 0; r < 4; r++) {
            float v = rsum[r];
            #pragma unroll
            for (int off = 8; off >= 1; off >>= 1) v += __shfl_xor(v, off, 64);
            l_i[r] = l_i[r] * alpha[r] + v;
            #pragma unroll
            for (int ct = 0; ct < 4; ct++) o[ct][r] *= alpha[r];
        }

        // O += P·V  (P from own wave's LDS strip; same-wave RAW via lgkmcnt)
        #pragma unroll
        for (int ks = 0; ks < 2; ks++) {
            bf16x8 afrag = *(const bf16x8*)&Ps[wave][l15][ks * 32 + quad * 8];
            #pragma unroll
            for (int ct = 0; ct < 4; ct++) {
                bf16x8 bfrag = *(const bf16x8*)&Vs[ct * 16 + l15][ks * 32 + quad * 8];
                o[ct] = __builtin_amdgcn_mfma_f32_16x16x32_bf16(afrag, bfrag, o[ct], 0, 0, 0);
            }
        }
    }

    // epilogue: normalize, store att [B,T,H,HD]
    #pragma unroll
    for (int r = 0; r < 4; r++) {
        float inv = 1.0f / l_i[r];
        int qg = q0 + wave * 16 + quad * 4 + r;
        bf16* orow = att + ((size_t)(bb * T_ + qg) * H_ + hh) * HD_;
        #pragma unroll
        for (int ct = 0; ct < 4; ct++)
            orow[ct * 16 + l15] = f2b(o[ct][r] * inv);
    }
}

// ---------------------------------------------------------------------------
// Kernel 3: output projection: out[m,n] = sum_f att[m,f] * Wo[n,f] + bo[n]
// ---------------------------------------------------------------------------
__global__ __launch_bounds__(256) void out_proj(
    const bf16* __restrict__ att, const float* __restrict__ Wo,
    const float* __restrict__ bo, float* __restrict__ out)
{
    const int m0 = blockIdx.x * 64;
    const int n0 = blockIdx.y * 64;

    __shared__ float As[16][64 + 1];
    __shared__ float Bs[16][64 + 1];

    const int tid = threadIdx.x;
    const int tx = tid & 15, ty = tid >> 4;
    float acc[4][4] = {};

    for (int k0 = 0; k0 < E_; k0 += 16) {
        {
            int row = tid >> 2, kk = (tid & 3) << 2;
            const bf16* p = att + (size_t)(m0 + row) * E_ + k0 + kk;
            #pragma unroll
            for (int i = 0; i < 4; i++) As[kk + i][row] = b2f(p[i]);
        }
        {
            int nn = tid >> 2, kk = (tid & 3) << 2;
            float4 b4 = *(const float4*)(Wo + (size_t)(n0 + nn) * E_ + k0 + kk);
            Bs[kk + 0][nn] = b4.x; Bs[kk + 1][nn] = b4.y;
            Bs[kk + 2][nn] = b4.z; Bs[kk + 3][nn] = b4.w;
        }
        __syncthreads();
        #pragma unroll
        for (int kk = 0; kk < 16; kk++) {
            float a[4], b[4];
            #pragma unroll
            for (int i = 0; i < 4; i++) a[i] = As[kk][ty * 4 + i];
            #pragma unroll
            for (int j = 0; j < 4; j++) b[j] = Bs[kk][tx * 4 + j];
            #pragma unroll
            for (int i = 0; i < 4; i++)
                #pragma unroll
                for (int j = 0; j < 4; j++) acc[i][j] += a[i] * b[j];
        }
        __syncthreads();
    }
    #pragma unroll
    for (int j = 0; j < 4; j++) {
        int n = n0 + tx * 4 + j;
        float bias = bo[n];
        #pragma unroll
        for (int i = 0; i < 4; i++) {
            int m = m0 + ty * 4 + i;
            out[(size_t)m * E_ + n] = acc[i][j] + bias;
        }
    }
}

// ---------------------------------------------------------------------------
extern "C" void kernel_launch(void* const* d_in, const int* in_sizes, int n_in,
                              void* d_out, int out_size, void* d_ws, size_t ws_size,
                              hipStream_t stream)
{
    const float* x  = (const float*)d_in[0];
    const float* Wq = (const float*)d_in[1];
    const float* Wk = (const float*)d_in[2];
    const float* Wv = (const float*)d_in[3];
    const float* Wo = (const float*)d_in[4];
    const float* bo = (const float*)d_in[5];
    float* out = (float*)d_out;

    const size_t elts = (size_t)B_ * H_ * T_ * HD_;   // 8,388,608
    bf16* q   = (bf16*)d_ws;          // [B,H,T,HD]
    bf16* k   = q + elts;             // [B,H,T,HD]
    bf16* v   = k + elts;             // [B,H,HD,T]  (transposed)
    bf16* att = v + elts;             // [B,T,H,HD]

    dim3 g_qkv((B_ * T_) / 64, E_ / 64, 3);
    qkv_gemm<<<g_qkv, 256, 0, stream>>>(x, Wq, Wk, Wv, q, k, v);

    flash_attn<<<dim3((T_ / 64) * B_ * H_), 256, 0, stream>>>(q, k, v, att);

    dim3 g_proj((B_ * T_) / 64, E_ / 64);
    out_proj<<<g_proj, 256, 0, stream>>>(att, Wo, bo, out);
}

// Round 5
// 349.496 us; speedup vs baseline: 31.9353x; 4.1518x over previous
//
#include <hip/hip_runtime.h>
#include <hip/hip_bf16.h>

// B=4, T=2048, E=1024, H=16, HD=64. fp32 in/out; bf16 intermediates in d_ws.
// Workspace layout (67,108,864 B total — the round-3-proven size):
//   [0 .. elts)        att region; Wt (6.3 MB) overlays its head until flash
//   [elts .. 2*elts)   q;  Wo_bf16 (2 MB) overlays its head after flash
//   [2*elts .. 3*elts) k
//   [3*elts .. 4*elts) v (transposed [B,H,HD,T])
#define B_  4
#define T_  2048
#define E_  1024
#define H_  16
#define HD_ 64

typedef __hip_bfloat16 bf16;
typedef unsigned short u16;
using bf16x8 = __attribute__((ext_vector_type(8))) short;
using f32x4  = __attribute__((ext_vector_type(4))) float;

__device__ __forceinline__ float b2f(bf16 x) { return __bfloat162float(x); }
__device__ __forceinline__ bf16  f2b(float x) { return __float2bfloat16(x); }
__device__ __forceinline__ u16 f2b_bits(float x) {
    union { bf16 h; u16 u; } cv; cv.h = __float2bfloat16(x); return cv.u;
}
__device__ __forceinline__ float bits2f(u16 u) {
    union { float f; unsigned int i; } cv; cv.i = ((unsigned int)u) << 16; return cv.f;
}

// ---------------------------------------------------------------------------
// Kernel 0a: elementwise fp32 -> bf16 cast (n divisible by 2048). Used for Wo.
// ---------------------------------------------------------------------------
__global__ __launch_bounds__(256) void cast_bf16(
    const float* __restrict__ src, bf16* __restrict__ dst)
{
    size_t i = ((size_t)blockIdx.x * 256 + threadIdx.x) * 8;
    float4 a = *(const float4*)(src + i);
    float4 b = *(const float4*)(src + i + 4);
    u16 o[8] = { f2b_bits(a.x), f2b_bits(a.y), f2b_bits(a.z), f2b_bits(a.w),
                 f2b_bits(b.x), f2b_bits(b.y), f2b_bits(b.z), f2b_bits(b.w) };
    *(uint4*)(dst + i) = *(const uint4*)o;
}

// ---------------------------------------------------------------------------
// Kernel 0b: cast + transpose Wq/Wk/Wv  [h][k][d] fp32 -> Wt [z][h][d][k] bf16
// so qkv B-fragments become contiguous ds_read_b128.
// ---------------------------------------------------------------------------
__global__ __launch_bounds__(256) void cast_w_t(
    const float* __restrict__ Wq, const float* __restrict__ Wk,
    const float* __restrict__ Wv, bf16* __restrict__ Wt)
{
    const float* W = (blockIdx.z == 0) ? Wq : (blockIdx.z == 1) ? Wk : Wv;
    bf16* dst = Wt + (size_t)blockIdx.z * (H_ * HD_ * E_);
    const int h = blockIdx.y, k0 = blockIdx.x * 64;
    __shared__ float Ws[64][65];
    const int tid = threadIdx.x;
    {
        int kk = tid >> 2, d0 = (tid & 3) * 16;
        const float* p = W + ((size_t)h * E_ + k0 + kk) * HD_ + d0;
        #pragma unroll
        for (int i = 0; i < 4; i++) {
            float4 f = *(const float4*)(p + i * 4);
            Ws[kk][d0 + i * 4 + 0] = f.x; Ws[kk][d0 + i * 4 + 1] = f.y;
            Ws[kk][d0 + i * 4 + 2] = f.z; Ws[kk][d0 + i * 4 + 3] = f.w;
        }
    }
    __syncthreads();
    {
        int d = tid >> 2, kc = (tid & 3) * 16;
        u16 o[16];
        #pragma unroll
        for (int j = 0; j < 16; j++) o[j] = f2b_bits(Ws[kc + j][d]);
        bf16* p = dst + ((size_t)h * HD_ + d) * E_ + k0 + kc;
        *(uint4*)(p)     = *(const uint4*)&o[0];
        *(uint4*)(p + 8) = *(const uint4*)&o[8];
    }
}

// ---------------------------------------------------------------------------
// Kernel 1: MFMA QKV projection. Block = (z,h | 256-row m-tile); 4 waves,
// wave-tile 64x64 (4x4 MFMA 16x16x32), BK=32. X is fp32, cast during LDS
// staging. Grid x = z*16+h (48 same-m blocks dispatch-adjacent -> x in L2).
// V written transposed [B,H,HD,T] via LDS-transpose epilogue.
// LDS union properly sized: max(staging 25,600 B, Vt 33,792 B).
// ---------------------------------------------------------------------------
__global__ __launch_bounds__(256, 3) void qkv_mfma(
    const float* __restrict__ x, const bf16* __restrict__ Wt,
    bf16* __restrict__ q, bf16* __restrict__ k, bf16* __restrict__ v)
{
    const int z = blockIdx.x >> 4;           // 0,1,2
    const int h = blockIdx.x & 15;
    const int m0 = blockIdx.y * 256;
    const bf16* Wz = Wt + (size_t)z * (H_ * HD_ * E_);
    bf16* out = (z == 0) ? q : (z == 1) ? k : v;
    const int tid = threadIdx.x, lane = tid & 63, w = tid >> 6;
    const int quad = lane >> 4, l15 = lane & 15;

    __shared__ __align__(16) u16 smem[64 * 264];     // 33,792 B
    u16 (*Xs)[40]  = (u16(*)[40])smem;               // [256 m][40]
    u16 (*Wsm)[40] = (u16(*)[40])(smem + 256 * 40);  // [64 d][40]

    f32x4 acc[4][4];
    #pragma unroll
    for (int i = 0; i < 4; i++)
        #pragma unroll
        for (int j = 0; j < 4; j++) acc[i][j] = f32x4{0.f, 0.f, 0.f, 0.f};

    for (int k0 = 0; k0 < E_; k0 += 32) {
        __syncthreads();
        {   // stage X[256][32] fp32->bf16 + W[64][32] bf16
            int rr = tid >> 2, c = (tid & 3) * 8;
            #pragma unroll
            for (int i = 0; i < 4; i++) {
                int row = i * 64 + rr;
                const float* p = x + (size_t)(m0 + row) * E_ + k0 + c;
                float4 f0 = *(const float4*)(p);
                float4 f1 = *(const float4*)(p + 4);
                u16 o[8] = { f2b_bits(f0.x), f2b_bits(f0.y), f2b_bits(f0.z), f2b_bits(f0.w),
                             f2b_bits(f1.x), f2b_bits(f1.y), f2b_bits(f1.z), f2b_bits(f1.w) };
                *(uint4*)&Xs[row][c] = *(const uint4*)o;
            }
            *(uint4*)&Wsm[rr][c] =
                *(const uint4*)(Wz + ((size_t)h * HD_ + rr) * E_ + k0 + c);
        }
        __syncthreads();

        bf16x8 af[4];
        #pragma unroll
        for (int i = 0; i < 4; i++)
            af[i] = *(const bf16x8*)&Xs[w * 64 + i * 16 + l15][quad * 8];
        #pragma unroll
        for (int j = 0; j < 4; j++) {
            bf16x8 bfr = *(const bf16x8*)&Wsm[j * 16 + l15][quad * 8];
            #pragma unroll
            for (int i = 0; i < 4; i++)
                acc[i][j] = __builtin_amdgcn_mfma_f32_16x16x32_bf16(af[i], bfr, acc[i][j], 0, 0, 0);
        }
    }

    if (z != 2) {
        // q,k: [B,H,T,HD]; C/D layout col=l15 (d), row=quad*4+r (t)
        #pragma unroll
        for (int i = 0; i < 4; i++)
            #pragma unroll
            for (int r = 0; r < 4; r++) {
                int m = m0 + w * 64 + i * 16 + quad * 4 + r;
                int bb = m >> 11, t = m & (T_ - 1);
                bf16* orow = out + ((size_t)(bb * H_ + h) * T_ + t) * HD_;
                #pragma unroll
                for (int j = 0; j < 4; j++)
                    orow[j * 16 + l15] = f2b(acc[i][j][r]);
            }
    } else {
        // v: transpose 256x64 -> [HD][256] in LDS, store [B,H,HD,T] coalesced
        u16 (*Vt)[264] = (u16(*)[264])smem;          // 33,792 B — fits now
        __syncthreads();                              // frag reads done
        #pragma unroll
        for (int i = 0; i < 4; i++)
            #pragma unroll
            for (int j = 0; j < 4; j++)
                #pragma unroll
                for (int r = 0; r < 4; r++)
                    Vt[j * 16 + l15][w * 64 + i * 16 + quad * 4 + r] = f2b_bits(acc[i][j][r]);
        __syncthreads();
        int d = tid >> 2, c = (tid & 3) * 64;
        int bb = m0 >> 11, t0 = m0 & (T_ - 1);
        bf16* dst = out + ((size_t)(bb * H_ + h) * HD_ + d) * T_ + t0 + c;
        #pragma unroll
        for (int u = 0; u < 8; u++)
            *(uint4*)(dst + u * 8) = *(const uint4*)&Vt[d][c + u * 8];
    }
}

// ---------------------------------------------------------------------------
// Kernel 2: MFMA flash attention (causal) — unchanged from round 3 (verified).
// ---------------------------------------------------------------------------
__global__ __launch_bounds__(256) void flash_attn(
    const bf16* __restrict__ q, const bf16* __restrict__ k,
    const bf16* __restrict__ vt, bf16* __restrict__ att)
{
    const int bh = blockIdx.x & 63;          // b*H + h
    const int qt = 31 - (blockIdx.x >> 6);   // heavy q-tiles dispatch first
    const int q0 = qt * 64;
    const int hh = bh & 15, bb = bh >> 4;
    const int tid = threadIdx.x, lane = tid & 63, wave = tid >> 6;
    const int quad = lane >> 4, l15 = lane & 15;

    __shared__ __align__(16) u16 Ks[64][72];
    __shared__ __align__(16) u16 Vs[64][72];
    __shared__ __align__(16) u16 Ps[4][16][72];

    const size_t baseK = (size_t)bh * T_ * HD_;
    const bf16* vbase = vt + (size_t)bh * (size_t)HD_ * T_;

    bf16x8 qfrag[2];
    {
        const bf16* qrow = q + baseK + (size_t)(q0 + wave * 16 + l15) * HD_;
        #pragma unroll
        for (int ks = 0; ks < 2; ks++)
            #pragma unroll
            for (int j = 0; j < 8; j++)
                ((short*)&qfrag[ks])[j] =
                    (short)f2b_bits(b2f(qrow[ks * 32 + quad * 8 + j]) * 0.125f);
    }

    f32x4 o[4];
    #pragma unroll
    for (int ct = 0; ct < 4; ct++) o[ct] = f32x4{0.f, 0.f, 0.f, 0.f};
    float m_i[4], l_i[4];
    #pragma unroll
    for (int r = 0; r < 4; r++) { m_i[r] = -1e30f; l_i[r] = 0.f; }

    for (int st = 0; st <= qt; st++) {
        const int s0 = st * 64;
        __syncthreads();
        {
            int r = tid >> 3, c = (tid & 7) * 8;
            *(uint4*)&Ks[r][c]      = *(const uint4*)(k + baseK + (size_t)(s0 + r) * HD_ + c);
            *(uint4*)&Ks[r + 32][c] = *(const uint4*)(k + baseK + (size_t)(s0 + r + 32) * HD_ + c);
            *(uint4*)&Vs[r][c]      = *(const uint4*)(vbase + (size_t)r * T_ + s0 + c);
            *(uint4*)&Vs[r + 32][c] = *(const uint4*)(vbase + (size_t)(r + 32) * T_ + s0 + c);
        }
        __syncthreads();

        f32x4 s[4];
        #pragma unroll
        for (int ct = 0; ct < 4; ct++) {
            f32x4 a = f32x4{0.f, 0.f, 0.f, 0.f};
            #pragma unroll
            for (int ks = 0; ks < 2; ks++) {
                bf16x8 bfrag = *(const bf16x8*)&Ks[ct * 16 + l15][ks * 32 + quad * 8];
                a = __builtin_amdgcn_mfma_f32_16x16x32_bf16(qfrag[ks], bfrag, a, 0, 0, 0);
            }
            s[ct] = a;
        }

        if (st == qt) {
            #pragma unroll
            for (int ct = 0; ct < 4; ct++) {
                int sg = ct * 16 + l15;
                #pragma unroll
                for (int r = 0; r < 4; r++) {
                    int qg = wave * 16 + quad * 4 + r;
                    if (sg > qg) s[ct][r] = -1e30f;
                }
            }
        }

        float alpha[4];
        #pragma unroll
        for (int r = 0; r < 4; r++) {
            float vmx = fmaxf(fmaxf(s[0][r], s[1][r]), fmaxf(s[2][r], s[3][r]));
            #pragma unroll
            for (int off = 8; off >= 1; off >>= 1) vmx = fmaxf(vmx, __shfl_xor(vmx, off, 64));
            float mn = fmaxf(m_i[r], vmx);
            alpha[r] = __expf(m_i[r] - mn);
            m_i[r] = mn;
        }

        float rsum[4] = {0.f, 0.f, 0.f, 0.f};
        #pragma unroll
        for (int ct = 0; ct < 4; ct++) {
            #pragma unroll
            for (int r = 0; r < 4; r++) {
                float p = __expf(s[ct][r] - m_i[r]);
                u16 pb = f2b_bits(p);
                rsum[r] += bits2f(pb);
                Ps[wave][quad * 4 + r][ct * 16 + l15] = pb;
            }
        }
        #pragma unroll
        for (int r = 0; r < 4; r++) {
            float vs = rsum[r];
            #pragma unroll
            for (int off = 8; off >= 1; off >>= 1) vs += __shfl_xor(vs, off, 64);
            l_i[r] = l_i[r] * alpha[r] + vs;
            #pragma unroll
            for (int ct = 0; ct < 4; ct++) o[ct][r] *= alpha[r];
        }

        #pragma unroll
        for (int ks = 0; ks < 2; ks++) {
            bf16x8 afrag = *(const bf16x8*)&Ps[wave][l15][ks * 32 + quad * 8];
            #pragma unroll
            for (int ct = 0; ct < 4; ct++) {
                bf16x8 bfrag = *(const bf16x8*)&Vs[ct * 16 + l15][ks * 32 + quad * 8];
                o[ct] = __builtin_amdgcn_mfma_f32_16x16x32_bf16(afrag, bfrag, o[ct], 0, 0, 0);
            }
        }
    }

    #pragma unroll
    for (int r = 0; r < 4; r++) {
        float inv = 1.0f / l_i[r];
        int qg = q0 + wave * 16 + quad * 4 + r;
        bf16* orow = att + ((size_t)(bb * T_ + qg) * H_ + hh) * HD_;
        #pragma unroll
        for (int ct = 0; ct < 4; ct++)
            orow[ct * 16 + l15] = f2b(o[ct][r] * inv);
    }
}

// ---------------------------------------------------------------------------
// Kernel 3: MFMA output projection. out[m,n] = sum_k att[m,k]*Wo[n,k] + bo[n].
// 128x128 tile, wave grid 2x2, wave-tile 64x64, BK=32.
// ---------------------------------------------------------------------------
__global__ __launch_bounds__(256, 3) void out_proj_mfma(
    const bf16* __restrict__ att, const bf16* __restrict__ Wob,
    const float* __restrict__ bo, float* __restrict__ out)
{
    const int m0 = blockIdx.x * 128, n0 = blockIdx.y * 128;
    const int tid = threadIdx.x, lane = tid & 63, w = tid >> 6;
    const int wm = w >> 1, wn = w & 1;
    const int quad = lane >> 4, l15 = lane & 15;

    __shared__ __align__(16) u16 As[128][40];
    __shared__ __align__(16) u16 Bs[128][40];

    f32x4 acc[4][4];
    #pragma unroll
    for (int i = 0; i < 4; i++)
        #pragma unroll
        for (int j = 0; j < 4; j++) acc[i][j] = f32x4{0.f, 0.f, 0.f, 0.f};

    for (int k0 = 0; k0 < E_; k0 += 32) {
        __syncthreads();
        {
            int rr = tid >> 2, c = (tid & 3) * 8;
            #pragma unroll
            for (int i = 0; i < 2; i++) {
                int row = i * 64 + rr;
                *(uint4*)&As[row][c] =
                    *(const uint4*)(att + (size_t)(m0 + row) * E_ + k0 + c);
                *(uint4*)&Bs[row][c] =
                    *(const uint4*)(Wob + (size_t)(n0 + row) * E_ + k0 + c);
            }
        }
        __syncthreads();

        bf16x8 af[4];
        #pragma unroll
        for (int i = 0; i < 4; i++)
            af[i] = *(const bf16x8*)&As[wm * 64 + i * 16 + l15][quad * 8];
        #pragma unroll
        for (int j = 0; j < 4; j++) {
            bf16x8 bfr = *(const bf16x8*)&Bs[wn * 64 + j * 16 + l15][quad * 8];
            #pragma unroll
            for (int i = 0; i < 4; i++)
                acc[i][j] = __builtin_amdgcn_mfma_f32_16x16x32_bf16(af[i], bfr, acc[i][j], 0, 0, 0);
        }
    }

    float bias[4];
    #pragma unroll
    for (int j = 0; j < 4; j++) bias[j] = bo[n0 + wn * 64 + j * 16 + l15];
    #pragma unroll
    for (int i = 0; i < 4; i++)
        #pragma unroll
        for (int r = 0; r < 4; r++) {
            int m = m0 + wm * 64 + i * 16 + quad * 4 + r;
            float* orow = out + (size_t)m * E_ + n0 + wn * 64;
            #pragma unroll
            for (int j = 0; j < 4; j++)
                orow[j * 16 + l15] = acc[i][j][r] + bias[j];
        }
}

// ---------------------------------------------------------------------------
extern "C" void kernel_launch(void* const* d_in, const int* in_sizes, int n_in,
                              void* d_out, int out_size, void* d_ws, size_t ws_size,
                              hipStream_t stream)
{
    const float* x  = (const float*)d_in[0];
    const float* Wq = (const float*)d_in[1];
    const float* Wk = (const float*)d_in[2];
    const float* Wv = (const float*)d_in[3];
    const float* Wo = (const float*)d_in[4];
    const float* bo = (const float*)d_in[5];
    float* out = (float*)d_out;

    const size_t elts = (size_t)B_ * H_ * T_ * HD_;   // 8,388,608
    bf16* att = (bf16*)d_ws;          // [B,T,H,HD]; Wt overlays head until flash
    bf16* Wt  = att;                  // [3][16][64][1024] = 6.3 MB (dead pre-flash)
    bf16* q   = att + elts;           // [B,H,T,HD]; Wob overlays head after flash
    bf16* Wob = q;                    // [1024][1024] = 2 MB (cast after flash)
    bf16* k   = q + elts;             // [B,H,T,HD]
    bf16* v   = k + elts;             // [B,H,HD,T] (transposed)  -> end 67.1 MB

    cast_w_t<<<dim3(E_ / 64, H_, 3), 256, 0, stream>>>(Wq, Wk, Wv, Wt);

    qkv_mfma<<<dim3(3 * H_, (B_ * T_) / 256), 256, 0, stream>>>(x, Wt, q, k, v);

    flash_attn<<<dim3((T_ / 64) * B_ * H_), 256, 0, stream>>>(q, k, v, att);

    cast_bf16<<<dim3((E_ * E_) / 2048), 256, 0, stream>>>(Wo, Wob);

    out_proj_mfma<<<dim3((B_ * T_) / 128, E_ / 128), 256, 0, stream>>>(att, Wob, bo, out);
}

// Round 6
// 329.603 us; speedup vs baseline: 33.8628x; 1.0604x over previous
//
#include <hip/hip_runtime.h>
#include <hip/hip_bf16.h>

// B=4, T=2048, E=1024, H=16, HD=64. fp32 in/out; bf16 intermediates in d_ws.
// Workspace layout (67,108,864 B, proven):
//   [0 .. elts)        att region; Wt (6.3 MB) overlays its head until flash
//   [elts .. 2*elts)   q;  Wo_bf16 (2 MB) overlays its head after flash
//   [2*elts .. 3*elts) k
//   [3*elts .. 4*elts) v (transposed [B,H,HD,T])
#define B_  4
#define T_  2048
#define E_  1024
#define H_  16
#define HD_ 64

typedef __hip_bfloat16 bf16;
typedef unsigned short u16;
using bf16x8 = __attribute__((ext_vector_type(8))) short;
using f32x4  = __attribute__((ext_vector_type(4))) float;

__device__ __forceinline__ float b2f(bf16 x) { return __bfloat162float(x); }
__device__ __forceinline__ bf16  f2b(float x) { return __float2bfloat16(x); }
__device__ __forceinline__ u16 f2b_bits(float x) {
    union { bf16 h; u16 u; } cv; cv.h = __float2bfloat16(x); return cv.u;
}
__device__ __forceinline__ float bits2f(u16 u) {
    union { float f; unsigned int i; } cv; cv.i = ((unsigned int)u) << 16; return cv.f;
}

// ---------------------------------------------------------------------------
// Kernel 0a: elementwise fp32 -> bf16 cast (n divisible by 2048). Used for Wo.
// ---------------------------------------------------------------------------
__global__ __launch_bounds__(256) void cast_bf16(
    const float* __restrict__ src, bf16* __restrict__ dst)
{
    size_t i = ((size_t)blockIdx.x * 256 + threadIdx.x) * 8;
    float4 a = *(const float4*)(src + i);
    float4 b = *(const float4*)(src + i + 4);
    u16 o[8] = { f2b_bits(a.x), f2b_bits(a.y), f2b_bits(a.z), f2b_bits(a.w),
                 f2b_bits(b.x), f2b_bits(b.y), f2b_bits(b.z), f2b_bits(b.w) };
    *(uint4*)(dst + i) = *(const uint4*)o;
}

// ---------------------------------------------------------------------------
// Kernel 0b: cast + transpose Wq/Wk/Wv [h][k][d] fp32 -> Wt [z][h][d][k] bf16.
// Wq (z==0) is pre-scaled by 1/sqrt(HD)=0.125 so flash skips the q-scale.
// ---------------------------------------------------------------------------
__global__ __launch_bounds__(256) void cast_w_t(
    const float* __restrict__ Wq, const float* __restrict__ Wk,
    const float* __restrict__ Wv, bf16* __restrict__ Wt)
{
    const float* W = (blockIdx.z == 0) ? Wq : (blockIdx.z == 1) ? Wk : Wv;
    const float scl = (blockIdx.z == 0) ? 0.125f : 1.0f;
    bf16* dst = Wt + (size_t)blockIdx.z * (H_ * HD_ * E_);
    const int h = blockIdx.y, k0 = blockIdx.x * 64;
    __shared__ float Ws[64][65];
    const int tid = threadIdx.x;
    {
        int kk = tid >> 2, d0 = (tid & 3) * 16;
        const float* p = W + ((size_t)h * E_ + k0 + kk) * HD_ + d0;
        #pragma unroll
        for (int i = 0; i < 4; i++) {
            float4 f = *(const float4*)(p + i * 4);
            Ws[kk][d0 + i * 4 + 0] = f.x; Ws[kk][d0 + i * 4 + 1] = f.y;
            Ws[kk][d0 + i * 4 + 2] = f.z; Ws[kk][d0 + i * 4 + 3] = f.w;
        }
    }
    __syncthreads();
    {
        int d = tid >> 2, kc = (tid & 3) * 16;
        u16 o[16];
        #pragma unroll
        for (int j = 0; j < 16; j++) o[j] = f2b_bits(Ws[kc + j][d] * scl);
        bf16* p = dst + ((size_t)h * HD_ + d) * E_ + k0 + kc;
        *(uint4*)(p)     = *(const uint4*)&o[0];
        *(uint4*)(p + 8) = *(const uint4*)&o[8];
    }
}

// ---------------------------------------------------------------------------
// Kernel 1: unified QKV GEMM. C[m][n] = sum_k x[m][k] * Wt_row[n][k],
// n = z*1024 + h*64 + d (Wt rows ARE output columns). 128x128 tile, 4 waves
// 2x2, wave-tile 64x64, BK=64. Rows padded to 72 u16 (16B-aligned, 2-way
// bank aliasing = free). x fp32, cast during staging. grid.x = n-tile so
// 24 consecutive blocks share one x m-strip (L2 reuse).
// V n-tiles get a 2-phase LDS-transpose epilogue -> v[B,H,HD,T].
// ---------------------------------------------------------------------------
__global__ __launch_bounds__(256) void qkv_mfma(
    const float* __restrict__ x, const bf16* __restrict__ Wt,
    bf16* __restrict__ q, bf16* __restrict__ k, bf16* __restrict__ v)
{
    const int n0 = blockIdx.x * 128;          // [0, 3072)
    const int m0 = blockIdx.y * 128;          // [0, 8192)
    const int z  = n0 >> 10;
    bf16* out = (z == 0) ? q : (z == 1) ? k : v;
    const int tid = threadIdx.x, lane = tid & 63, w = tid >> 6;
    const int wm = w >> 1, wn = w & 1;
    const int quad = lane >> 4, l15 = lane & 15;

    __shared__ __align__(16) u16 smem[2 * 128 * 72];   // 36,864 B
    u16 (*As)[72] = (u16(*)[72])smem;                  // [128 m][72]
    u16 (*Bs)[72] = (u16(*)[72])(smem + 128 * 72);     // [128 n][72]

    f32x4 acc[4][4];
    #pragma unroll
    for (int i = 0; i < 4; i++)
        #pragma unroll
        for (int j = 0; j < 4; j++) acc[i][j] = f32x4{0.f, 0.f, 0.f, 0.f};

    const int arow = tid >> 1, ac = (tid & 1) * 32;
    for (int k0 = 0; k0 < E_; k0 += 64) {
        __syncthreads();
        {   // A: x[128][64] fp32 -> bf16; B: Wt[128][64] bf16 copy
            const float* xp = x + (size_t)(m0 + arow) * E_ + k0 + ac;
            #pragma unroll
            for (int u = 0; u < 4; u++) {
                float4 f0 = *(const float4*)(xp + u * 8);
                float4 f1 = *(const float4*)(xp + u * 8 + 4);
                u16 o8[8] = { f2b_bits(f0.x), f2b_bits(f0.y), f2b_bits(f0.z), f2b_bits(f0.w),
                              f2b_bits(f1.x), f2b_bits(f1.y), f2b_bits(f1.z), f2b_bits(f1.w) };
                *(uint4*)&As[arow][ac + u * 8] = *(const uint4*)o8;
            }
            const bf16* wp = Wt + (size_t)(n0 + arow) * E_ + k0 + ac;
            #pragma unroll
            for (int u = 0; u < 4; u++)
                *(uint4*)&Bs[arow][ac + u * 8] = *(const uint4*)(wp + u * 8);
        }
        __syncthreads();

        #pragma unroll
        for (int ks = 0; ks < 2; ks++) {
            bf16x8 af[4];
            #pragma unroll
            for (int i = 0; i < 4; i++)
                af[i] = *(const bf16x8*)&As[wm * 64 + i * 16 + l15][ks * 32 + quad * 8];
            #pragma unroll
            for (int j = 0; j < 4; j++) {
                bf16x8 bfr = *(const bf16x8*)&Bs[wn * 64 + j * 16 + l15][ks * 32 + quad * 8];
                #pragma unroll
                for (int i = 0; i < 4; i++)
                    acc[i][j] = __builtin_amdgcn_mfma_f32_16x16x32_bf16(af[i], bfr, acc[i][j], 0, 0, 0);
            }
        }
    }

    if (z != 2) {
        // q,k: [B,H,T,HD]; wave's 64 cols = one head exactly
        const int h = ((n0 & 1023) >> 6) + wn;
        #pragma unroll
        for (int i = 0; i < 4; i++)
            #pragma unroll
            for (int r = 0; r < 4; r++) {
                int m = m0 + wm * 64 + i * 16 + quad * 4 + r;
                int bb2 = m >> 11, t = m & (T_ - 1);
                bf16* orow = out + ((size_t)(bb2 * H_ + h) * T_ + t) * HD_;
                #pragma unroll
                for (int j = 0; j < 4; j++)
                    orow[j * 16 + l15] = f2b(acc[i][j][r]);
            }
    } else {
        // v: transpose per 64-d half (one head) in LDS -> [B,H,HD,T]
        u16 (*Vt)[136] = (u16(*)[136])smem;            // [64][136] = 17,408 B
        const int bb2 = m0 >> 11, t0 = m0 & (T_ - 1);
        #pragma unroll
        for (int half = 0; half < 2; half++) {
            __syncthreads();                            // prior reads/stores done
            if (wn == half) {
                #pragma unroll
                for (int j = 0; j < 4; j++)
                    #pragma unroll
                    for (int i = 0; i < 4; i++) {
                        ushort4 pk;
                        pk.x = f2b_bits(acc[i][j][0]);
                        pk.y = f2b_bits(acc[i][j][1]);
                        pk.z = f2b_bits(acc[i][j][2]);
                        pk.w = f2b_bits(acc[i][j][3]);
                        *(ushort4*)&Vt[j * 16 + l15][wm * 64 + i * 16 + quad * 4] = pk;
                    }
            }
            __syncthreads();
            {
                int dd = tid >> 2, tt = (tid & 3) * 32;
                int h = ((n0 & 1023) >> 6) + half;
                bf16* dst = out + ((size_t)(bb2 * H_ + h) * HD_ + dd) * T_ + t0 + tt;
                #pragma unroll
                for (int u = 0; u < 4; u++)
                    *(uint4*)(dst + u * 8) = *(const uint4*)&Vt[dd][tt + u * 8];
            }
        }
    }
}

// ---------------------------------------------------------------------------
// Kernel 2: MFMA flash attention, S^T formulation. Block = 4 waves; wave owns
// 16 q (n-dim), iterates 64-s tiles. S^T = K·Q^T: mfma(A=Kfrag, B=Qfrag) ->
// C col=l15=q, row=quad*4+r=s: each lane holds 16 s-values for ONE q ->
// softmax reduction = 15 in-reg ops + 2 shuffles; m/l/alpha per-lane scalars.
// P^T stored [q][s] in LDS via ds_write_b64; PV: O^T = V^T·P^T with both
// fragments contiguous b128. O^T stored via 8B packs.
// ---------------------------------------------------------------------------
__global__ __launch_bounds__(256) void flash_attn(
    const bf16* __restrict__ q, const bf16* __restrict__ k,
    const bf16* __restrict__ vt, bf16* __restrict__ att)
{
    const int bh = blockIdx.x & 63;          // b*H + h
    const int qt = 31 - (blockIdx.x >> 6);   // heavy q-tiles dispatch first
    const int q0 = qt * 64;
    const int hh = bh & 15, bb = bh >> 4;
    const int tid = threadIdx.x, lane = tid & 63, wave = tid >> 6;
    const int quad = lane >> 4, l15 = lane & 15;

    __shared__ __align__(16) u16 Ks[64][72];       // K[s][d]
    __shared__ __align__(16) u16 Vs[64][72];       // V^T: Vs[d][s]
    __shared__ __align__(16) u16 P2[4][16][72];    // per-wave P[q][s]

    const size_t baseK = (size_t)bh * T_ * HD_;
    const bf16* vbase = vt + (size_t)bh * (size_t)HD_ * T_;

    // Q fragment (B-operand of S^T): B[k=ks*32+quad*8+j][n=q=l15]
    const int qg = q0 + wave * 16 + l15;
    const bf16* qrow = q + baseK + (size_t)qg * HD_;   // pre-scaled by 1/8
    bf16x8 qfrag[2];
    qfrag[0] = *(const bf16x8*)(qrow + quad * 8);
    qfrag[1] = *(const bf16x8*)(qrow + 32 + quad * 8);

    f32x4 o[4];   // O^T: o[dt][r] = O^T[d=dt*16+quad*4+r][q=l15]
    #pragma unroll
    for (int dt = 0; dt < 4; dt++) o[dt] = f32x4{0.f, 0.f, 0.f, 0.f};
    float m_i = -1e30f, l_i = 0.f;

    const int q_in = wave * 16 + l15;        // q index within the 64-tile

    for (int st = 0; st <= qt; st++) {
        const int s0 = st * 64;
        __syncthreads();
        {   // stage K tile + V^T tile
            int r = tid >> 3, c = (tid & 7) * 8;
            *(uint4*)&Ks[r][c]      = *(const uint4*)(k + baseK + (size_t)(s0 + r) * HD_ + c);
            *(uint4*)&Ks[r + 32][c] = *(const uint4*)(k + baseK + (size_t)(s0 + r + 32) * HD_ + c);
            *(uint4*)&Vs[r][c]      = *(const uint4*)(vbase + (size_t)r * T_ + s0 + c);
            *(uint4*)&Vs[r + 32][c] = *(const uint4*)(vbase + (size_t)(r + 32) * T_ + s0 + c);
        }
        __syncthreads();

        // S^T: 4 s-tiles; A = K rows (m=s), B = Q rows (n=q)
        f32x4 s[4];
        #pragma unroll
        for (int ct = 0; ct < 4; ct++) {
            f32x4 a = f32x4{0.f, 0.f, 0.f, 0.f};
            #pragma unroll
            for (int ks = 0; ks < 2; ks++) {
                bf16x8 kfrag = *(const bf16x8*)&Ks[ct * 16 + l15][ks * 32 + quad * 8];
                a = __builtin_amdgcn_mfma_f32_16x16x32_bf16(kfrag, qfrag[ks], a, 0, 0, 0);
            }
            s[ct] = a;
        }

        if (st == qt) {   // diagonal: mask s > q (tile-local indices)
            #pragma unroll
            for (int ct = 0; ct < 4; ct++) {
                int sbase = ct * 16 + quad * 4;
                #pragma unroll
                for (int r = 0; r < 4; r++)
                    if (sbase + r > q_in) s[ct][r] = -1e30f;
            }
        }

        // tile max: 16 in-register values + 2 cross-quad shuffles
        float tm = fmaxf(fmaxf(fmaxf(s[0][0], s[0][1]), fmaxf(s[0][2], s[0][3])),
                         fmaxf(fmaxf(s[1][0], s[1][1]), fmaxf(s[1][2], s[1][3])));
        tm = fmaxf(tm, fmaxf(fmaxf(fmaxf(s[2][0], s[2][1]), fmaxf(s[2][2], s[2][3])),
                             fmaxf(fmaxf(s[3][0], s[3][1]), fmaxf(s[3][2], s[3][3]))));
        tm = fmaxf(tm, __shfl_xor(tm, 16, 64));
        tm = fmaxf(tm, __shfl_xor(tm, 32, 64));
        float mn = fmaxf(m_i, tm);
        float alpha = __expf(m_i - mn);
        m_i = mn;

        // P = exp(S - m) -> bf16; b64 writes into P2[q][s]; sum rounded vals
        float rsum = 0.f;
        #pragma unroll
        for (int ct = 0; ct < 4; ct++) {
            ushort4 pk;
            float p0 = __expf(s[ct][0] - m_i); pk.x = f2b_bits(p0);
            float p1 = __expf(s[ct][1] - m_i); pk.y = f2b_bits(p1);
            float p2 = __expf(s[ct][2] - m_i); pk.z = f2b_bits(p2);
            float p3 = __expf(s[ct][3] - m_i); pk.w = f2b_bits(p3);
            rsum += bits2f(pk.x) + bits2f(pk.y) + bits2f(pk.z) + bits2f(pk.w);
            *(ushort4*)&P2[wave][l15][ct * 16 + quad * 4] = pk;
        }
        rsum += __shfl_xor(rsum, 16, 64);
        rsum += __shfl_xor(rsum, 32, 64);
        l_i = l_i * alpha + rsum;
        #pragma unroll
        for (int dt = 0; dt < 4; dt++)
            #pragma unroll
            for (int r = 0; r < 4; r++) o[dt][r] *= alpha;

        // O^T += V^T · P^T   (same-wave LDS RAW on P2 -> lgkmcnt handles)
        #pragma unroll
        for (int ks = 0; ks < 2; ks++) {
            bf16x8 pfrag = *(const bf16x8*)&P2[wave][l15][ks * 32 + quad * 8];
            #pragma unroll
            for (int dt = 0; dt < 4; dt++) {
                bf16x8 vfrag = *(const bf16x8*)&Vs[dt * 16 + l15][ks * 32 + quad * 8];
                o[dt] = __builtin_amdgcn_mfma_f32_16x16x32_bf16(vfrag, pfrag, o[dt], 0, 0, 0);
            }
        }
    }

    // epilogue: lane owns q=qg; d = dt*16 + quad*4 + r (r contiguous -> 8B packs)
    float inv = 1.0f / l_i;
    bf16* orow = att + ((size_t)(bb * T_ + qg) * H_ + hh) * HD_;
    #pragma unroll
    for (int dt = 0; dt < 4; dt++) {
        ushort4 pk;
        pk.x = f2b_bits(o[dt][0] * inv);
        pk.y = f2b_bits(o[dt][1] * inv);
        pk.z = f2b_bits(o[dt][2] * inv);
        pk.w = f2b_bits(o[dt][3] * inv);
        *(ushort4*)(orow + dt * 16 + quad * 4) = pk;
    }
}

// ---------------------------------------------------------------------------
// Kernel 3: MFMA output projection. out[m,n] = sum_k att[m,k]*Wo[n,k] + bo[n].
// 128x128 tile, wave grid 2x2, wave-tile 64x64, BK=32.
// ---------------------------------------------------------------------------
__global__ __launch_bounds__(256, 3) void out_proj_mfma(
    const bf16* __restrict__ att, const bf16* __restrict__ Wob,
    const float* __restrict__ bo, float* __restrict__ out)
{
    const int m0 = blockIdx.x * 128, n0 = blockIdx.y * 128;
    const int tid = threadIdx.x, lane = tid & 63, w = tid >> 6;
    const int wm = w >> 1, wn = w & 1;
    const int quad = lane >> 4, l15 = lane & 15;

    __shared__ __align__(16) u16 As[128][40];
    __shared__ __align__(16) u16 Bs[128][40];

    f32x4 acc[4][4];
    #pragma unroll
    for (int i = 0; i < 4; i++)
        #pragma unroll
        for (int j = 0; j < 4; j++) acc[i][j] = f32x4{0.f, 0.f, 0.f, 0.f};

    for (int k0 = 0; k0 < E_; k0 += 32) {
        __syncthreads();
        {
            int rr = tid >> 2, c = (tid & 3) * 8;
            #pragma unroll
            for (int i = 0; i < 2; i++) {
                int row = i * 64 + rr;
                *(uint4*)&As[row][c] =
                    *(const uint4*)(att + (size_t)(m0 + row) * E_ + k0 + c);
                *(uint4*)&Bs[row][c] =
                    *(const uint4*)(Wob + (size_t)(n0 + row) * E_ + k0 + c);
            }
        }
        __syncthreads();

        bf16x8 af[4];
        #pragma unroll
        for (int i = 0; i < 4; i++)
            af[i] = *(const bf16x8*)&As[wm * 64 + i * 16 + l15][quad * 8];
        #pragma unroll
        for (int j = 0; j < 4; j++) {
            bf16x8 bfr = *(const bf16x8*)&Bs[wn * 64 + j * 16 + l15][quad * 8];
            #pragma unroll
            for (int i = 0; i < 4; i++)
                acc[i][j] = __builtin_amdgcn_mfma_f32_16x16x32_bf16(af[i], bfr, acc[i][j], 0, 0, 0);
        }
    }

    float bias[4];
    #pragma unroll
    for (int j = 0; j < 4; j++) bias[j] = bo[n0 + wn * 64 + j * 16 + l15];
    #pragma unroll
    for (int i = 0; i < 4; i++)
        #pragma unroll
        for (int r = 0; r < 4; r++) {
            int m = m0 + wm * 64 + i * 16 + quad * 4 + r;
            float* orow = out + (size_t)m * E_ + n0 + wn * 64;
            #pragma unroll
            for (int j = 0; j < 4; j++)
                orow[j * 16 + l15] = acc[i][j][r] + bias[j];
        }
}

// ---------------------------------------------------------------------------
extern "C" void kernel_launch(void* const* d_in, const int* in_sizes, int n_in,
                              void* d_out, int out_size, void* d_ws, size_t ws_size,
                              hipStream_t stream)
{
    const float* x  = (const float*)d_in[0];
    const float* Wq = (const float*)d_in[1];
    const float* Wk = (const float*)d_in[2];
    const float* Wv = (const float*)d_in[3];
    const float* Wo = (const float*)d_in[4];
    const float* bo = (const float*)d_in[5];
    float* out = (float*)d_out;

    const size_t elts = (size_t)B_ * H_ * T_ * HD_;   // 8,388,608
    bf16* att = (bf16*)d_ws;          // [B,T,H,HD]; Wt overlays head until flash
    bf16* Wt  = att;                  // [3][16][64][1024] = 6.3 MB (dead pre-flash)
    bf16* q   = att + elts;           // [B,H,T,HD]; Wob overlays head after flash
    bf16* Wob = q;                    // [1024][1024] = 2 MB (cast after flash)
    bf16* k   = q + elts;             // [B,H,T,HD]
    bf16* v   = k + elts;             // [B,H,HD,T] (transposed)  -> end 67.1 MB

    cast_w_t<<<dim3(E_ / 64, H_, 3), 256, 0, stream>>>(Wq, Wk, Wv, Wt);

    qkv_mfma<<<dim3(3 * E_ / 128, (B_ * T_) / 128), 256, 0, stream>>>(x, Wt, q, k, v);

    flash_attn<<<dim3((T_ / 64) * B_ * H_), 256, 0, stream>>>(q, k, v, att);

    cast_bf16<<<dim3((E_ * E_) / 2048), 256, 0, stream>>>(Wo, Wob);

    out_proj_mfma<<<dim3((B_ * T_) / 128, E_ / 128), 256, 0, stream>>>(att, Wob, bo, out);
}

// Round 7
// 286.702 us; speedup vs baseline: 38.9299x; 1.1496x over previous
//
#include <hip/hip_runtime.h>
#include <hip/hip_bf16.h>

// B=4, T=2048, E=1024, H=16, HD=64. fp32 in/out; bf16 intermediates in d_ws.
// Workspace layout (67,108,864 B, proven):
//   [0 .. elts)        att region; Wt (6.3 MB) overlays its head until flash
//   [elts .. 2*elts)   q;  Wo_bf16 (2 MB) overlays its head after flash
//   [2*elts .. 3*elts) k
//   [3*elts .. 4*elts) v (transposed [B,H,HD,T])
// Extra scratch: xb (bf16 x, 16.7 MB) lives in the FIRST HALF OF d_out —
// legal because out_proj fully overwrites d_out afterwards.
#define B_  4
#define T_  2048
#define E_  1024
#define H_  16
#define HD_ 64

typedef __hip_bfloat16 bf16;
typedef unsigned short u16;
using bf16x8 = __attribute__((ext_vector_type(8))) short;
using f32x4  = __attribute__((ext_vector_type(4))) float;

__device__ __forceinline__ float b2f(bf16 x) { return __bfloat162float(x); }
__device__ __forceinline__ bf16  f2b(float x) { return __float2bfloat16(x); }
__device__ __forceinline__ u16 f2b_bits(float x) {
    union { bf16 h; u16 u; } cv; cv.h = __float2bfloat16(x); return cv.u;
}
__device__ __forceinline__ float bits2f(u16 u) {
    union { float f; unsigned int i; } cv; cv.i = ((unsigned int)u) << 16; return cv.f;
}

// ---------------------------------------------------------------------------
// Kernel 0a: elementwise fp32 -> bf16 cast (n divisible by 2048).
// ---------------------------------------------------------------------------
__global__ __launch_bounds__(256) void cast_bf16(
    const float* __restrict__ src, bf16* __restrict__ dst)
{
    size_t i = ((size_t)blockIdx.x * 256 + threadIdx.x) * 8;
    float4 a = *(const float4*)(src + i);
    float4 b = *(const float4*)(src + i + 4);
    u16 o[8] = { f2b_bits(a.x), f2b_bits(a.y), f2b_bits(a.z), f2b_bits(a.w),
                 f2b_bits(b.x), f2b_bits(b.y), f2b_bits(b.z), f2b_bits(b.w) };
    *(uint4*)(dst + i) = *(const uint4*)o;
}

// ---------------------------------------------------------------------------
// Kernel 0b: cast + transpose Wq/Wk/Wv [h][k][d] fp32 -> Wt [z][h][d][k] bf16.
// Wq (z==0) is pre-scaled by 1/sqrt(HD)=0.125 so flash skips the q-scale.
// ---------------------------------------------------------------------------
__global__ __launch_bounds__(256) void cast_w_t(
    const float* __restrict__ Wq, const float* __restrict__ Wk,
    const float* __restrict__ Wv, bf16* __restrict__ Wt)
{
    const float* W = (blockIdx.z == 0) ? Wq : (blockIdx.z == 1) ? Wk : Wv;
    const float scl = (blockIdx.z == 0) ? 0.125f : 1.0f;
    bf16* dst = Wt + (size_t)blockIdx.z * (H_ * HD_ * E_);
    const int h = blockIdx.y, k0 = blockIdx.x * 64;
    __shared__ float Ws[64][65];
    const int tid = threadIdx.x;
    {
        int kk = tid >> 2, d0 = (tid & 3) * 16;
        const float* p = W + ((size_t)h * E_ + k0 + kk) * HD_ + d0;
        #pragma unroll
        for (int i = 0; i < 4; i++) {
            float4 f = *(const float4*)(p + i * 4);
            Ws[kk][d0 + i * 4 + 0] = f.x; Ws[kk][d0 + i * 4 + 1] = f.y;
            Ws[kk][d0 + i * 4 + 2] = f.z; Ws[kk][d0 + i * 4 + 3] = f.w;
        }
    }
    __syncthreads();
    {
        int d = tid >> 2, kc = (tid & 3) * 16;
        u16 o[16];
        #pragma unroll
        for (int j = 0; j < 16; j++) o[j] = f2b_bits(Ws[kc + j][d] * scl);
        bf16* p = dst + ((size_t)h * HD_ + d) * E_ + k0 + kc;
        *(uint4*)(p)     = *(const uint4*)&o[0];
        *(uint4*)(p + 8) = *(const uint4*)&o[8];
    }
}

// ---------------------------------------------------------------------------
// Kernel 1: unified QKV GEMM, all-bf16 staging. C[m][n] = xb[m][:]·Wt[n][:],
// n = z*1024 + h*64 + d. 128x128 tile, 4 waves 2x2, wave-tile 64x64, BK=64.
// Rows padded to 72 u16 (16B-aligned, 2-way bank aliasing = free).
// Staging is 4+4 uint4 copies per thread per iter (no cast in loop).
// V n-tiles get a 2-phase LDS-transpose epilogue -> v[B,H,HD,T].
// ---------------------------------------------------------------------------
__global__ __launch_bounds__(256) void qkv_mfma(
    const bf16* __restrict__ xb, const bf16* __restrict__ Wt,
    bf16* __restrict__ q, bf16* __restrict__ k, bf16* __restrict__ v)
{
    const int n0 = blockIdx.x * 128;          // [0, 3072)
    const int m0 = blockIdx.y * 128;          // [0, 8192)
    const int z  = n0 >> 10;
    bf16* out = (z == 0) ? q : (z == 1) ? k : v;
    const int tid = threadIdx.x, lane = tid & 63, w = tid >> 6;
    const int wm = w >> 1, wn = w & 1;
    const int quad = lane >> 4, l15 = lane & 15;

    __shared__ __align__(16) u16 smem[2 * 128 * 72];   // 36,864 B
    u16 (*As)[72] = (u16(*)[72])smem;                  // [128 m][72]
    u16 (*Bs)[72] = (u16(*)[72])(smem + 128 * 72);     // [128 n][72]

    f32x4 acc[4][4];
    #pragma unroll
    for (int i = 0; i < 4; i++)
        #pragma unroll
        for (int j = 0; j < 4; j++) acc[i][j] = f32x4{0.f, 0.f, 0.f, 0.f};

    const int arow = tid >> 1, ac = (tid & 1) * 32;
    for (int k0 = 0; k0 < E_; k0 += 64) {
        __syncthreads();
        {   // A: xb[128][64] copy; B: Wt[128][64] copy (all uint4)
            const bf16* xp = xb + (size_t)(m0 + arow) * E_ + k0 + ac;
            const bf16* wp = Wt + (size_t)(n0 + arow) * E_ + k0 + ac;
            #pragma unroll
            for (int u = 0; u < 4; u++) {
                *(uint4*)&As[arow][ac + u * 8] = *(const uint4*)(xp + u * 8);
                *(uint4*)&Bs[arow][ac + u * 8] = *(const uint4*)(wp + u * 8);
            }
        }
        __syncthreads();

        #pragma unroll
        for (int ks = 0; ks < 2; ks++) {
            bf16x8 af[4];
            #pragma unroll
            for (int i = 0; i < 4; i++)
                af[i] = *(const bf16x8*)&As[wm * 64 + i * 16 + l15][ks * 32 + quad * 8];
            #pragma unroll
            for (int j = 0; j < 4; j++) {
                bf16x8 bfr = *(const bf16x8*)&Bs[wn * 64 + j * 16 + l15][ks * 32 + quad * 8];
                #pragma unroll
                for (int i = 0; i < 4; i++)
                    acc[i][j] = __builtin_amdgcn_mfma_f32_16x16x32_bf16(af[i], bfr, acc[i][j], 0, 0, 0);
            }
        }
    }

    if (z != 2) {
        // q,k: [B,H,T,HD]; wave's 64 cols = one head exactly
        const int h = ((n0 & 1023) >> 6) + wn;
        #pragma unroll
        for (int i = 0; i < 4; i++)
            #pragma unroll
            for (int r = 0; r < 4; r++) {
                int m = m0 + wm * 64 + i * 16 + quad * 4 + r;
                int bb2 = m >> 11, t = m & (T_ - 1);
                bf16* orow = out + ((size_t)(bb2 * H_ + h) * T_ + t) * HD_;
                #pragma unroll
                for (int j = 0; j < 4; j++)
                    orow[j * 16 + l15] = f2b(acc[i][j][r]);
            }
    } else {
        // v: transpose per 64-d half (one head) in LDS -> [B,H,HD,T]
        u16 (*Vt)[136] = (u16(*)[136])smem;            // [64][136] = 17,408 B
        const int bb2 = m0 >> 11, t0 = m0 & (T_ - 1);
        #pragma unroll
        for (int half = 0; half < 2; half++) {
            __syncthreads();                            // prior reads/stores done
            if (wn == half) {
                #pragma unroll
                for (int j = 0; j < 4; j++)
                    #pragma unroll
                    for (int i = 0; i < 4; i++) {
                        ushort4 pk;
                        pk.x = f2b_bits(acc[i][j][0]);
                        pk.y = f2b_bits(acc[i][j][1]);
                        pk.z = f2b_bits(acc[i][j][2]);
                        pk.w = f2b_bits(acc[i][j][3]);
                        *(ushort4*)&Vt[j * 16 + l15][wm * 64 + i * 16 + quad * 4] = pk;
                    }
            }
            __syncthreads();
            {
                int dd = tid >> 2, tt = (tid & 3) * 32;
                int h = ((n0 & 1023) >> 6) + half;
                bf16* dst = out + ((size_t)(bb2 * H_ + h) * HD_ + dd) * T_ + t0 + tt;
                #pragma unroll
                for (int u = 0; u < 4; u++)
                    *(uint4*)(dst + u * 8) = *(const uint4*)&Vt[dd][tt + u * 8];
            }
        }
    }
}

// ---------------------------------------------------------------------------
// Kernel 2: MFMA flash attention, S^T formulation — unchanged from round 6.
// ---------------------------------------------------------------------------
__global__ __launch_bounds__(256) void flash_attn(
    const bf16* __restrict__ q, const bf16* __restrict__ k,
    const bf16* __restrict__ vt, bf16* __restrict__ att)
{
    const int bh = blockIdx.x & 63;          // b*H + h
    const int qt = 31 - (blockIdx.x >> 6);   // heavy q-tiles dispatch first
    const int q0 = qt * 64;
    const int hh = bh & 15, bb = bh >> 4;
    const int tid = threadIdx.x, lane = tid & 63, wave = tid >> 6;
    const int quad = lane >> 4, l15 = lane & 15;

    __shared__ __align__(16) u16 Ks[64][72];       // K[s][d]
    __shared__ __align__(16) u16 Vs[64][72];       // V^T: Vs[d][s]
    __shared__ __align__(16) u16 P2[4][16][72];    // per-wave P[q][s]

    const size_t baseK = (size_t)bh * T_ * HD_;
    const bf16* vbase = vt + (size_t)bh * (size_t)HD_ * T_;

    const int qg = q0 + wave * 16 + l15;
    const bf16* qrow = q + baseK + (size_t)qg * HD_;   // pre-scaled by 1/8
    bf16x8 qfrag[2];
    qfrag[0] = *(const bf16x8*)(qrow + quad * 8);
    qfrag[1] = *(const bf16x8*)(qrow + 32 + quad * 8);

    f32x4 o[4];
    #pragma unroll
    for (int dt = 0; dt < 4; dt++) o[dt] = f32x4{0.f, 0.f, 0.f, 0.f};
    float m_i = -1e30f, l_i = 0.f;

    const int q_in = wave * 16 + l15;

    for (int st = 0; st <= qt; st++) {
        const int s0 = st * 64;
        __syncthreads();
        {
            int r = tid >> 3, c = (tid & 7) * 8;
            *(uint4*)&Ks[r][c]      = *(const uint4*)(k + baseK + (size_t)(s0 + r) * HD_ + c);
            *(uint4*)&Ks[r + 32][c] = *(const uint4*)(k + baseK + (size_t)(s0 + r + 32) * HD_ + c);
            *(uint4*)&Vs[r][c]      = *(const uint4*)(vbase + (size_t)r * T_ + s0 + c);
            *(uint4*)&Vs[r + 32][c] = *(const uint4*)(vbase + (size_t)(r + 32) * T_ + s0 + c);
        }
        __syncthreads();

        f32x4 s[4];
        #pragma unroll
        for (int ct = 0; ct < 4; ct++) {
            f32x4 a = f32x4{0.f, 0.f, 0.f, 0.f};
            #pragma unroll
            for (int ks = 0; ks < 2; ks++) {
                bf16x8 kfrag = *(const bf16x8*)&Ks[ct * 16 + l15][ks * 32 + quad * 8];
                a = __builtin_amdgcn_mfma_f32_16x16x32_bf16(kfrag, qfrag[ks], a, 0, 0, 0);
            }
            s[ct] = a;
        }

        if (st == qt) {
            #pragma unroll
            for (int ct = 0; ct < 4; ct++) {
                int sbase = ct * 16 + quad * 4;
                #pragma unroll
                for (int r = 0; r < 4; r++)
                    if (sbase + r > q_in) s[ct][r] = -1e30f;
            }
        }

        float tm = fmaxf(fmaxf(fmaxf(s[0][0], s[0][1]), fmaxf(s[0][2], s[0][3])),
                         fmaxf(fmaxf(s[1][0], s[1][1]), fmaxf(s[1][2], s[1][3])));
        tm = fmaxf(tm, fmaxf(fmaxf(fmaxf(s[2][0], s[2][1]), fmaxf(s[2][2], s[2][3])),
                             fmaxf(fmaxf(s[3][0], s[3][1]), fmaxf(s[3][2], s[3][3]))));
        tm = fmaxf(tm, __shfl_xor(tm, 16, 64));
        tm = fmaxf(tm, __shfl_xor(tm, 32, 64));
        float mn = fmaxf(m_i, tm);
        float alpha = __expf(m_i - mn);
        m_i = mn;

        float rsum = 0.f;
        #pragma unroll
        for (int ct = 0; ct < 4; ct++) {
            ushort4 pk;
            float p0 = __expf(s[ct][0] - m_i); pk.x = f2b_bits(p0);
            float p1 = __expf(s[ct][1] - m_i); pk.y = f2b_bits(p1);
            float p2 = __expf(s[ct][2] - m_i); pk.z = f2b_bits(p2);
            float p3 = __expf(s[ct][3] - m_i); pk.w = f2b_bits(p3);
            rsum += bits2f(pk.x) + bits2f(pk.y) + bits2f(pk.z) + bits2f(pk.w);
            *(ushort4*)&P2[wave][l15][ct * 16 + quad * 4] = pk;
        }
        rsum += __shfl_xor(rsum, 16, 64);
        rsum += __shfl_xor(rsum, 32, 64);
        l_i = l_i * alpha + rsum;
        #pragma unroll
        for (int dt = 0; dt < 4; dt++)
            #pragma unroll
            for (int r = 0; r < 4; r++) o[dt][r] *= alpha;

        #pragma unroll
        for (int ks = 0; ks < 2; ks++) {
            bf16x8 pfrag = *(const bf16x8*)&P2[wave][l15][ks * 32 + quad * 8];
            #pragma unroll
            for (int dt = 0; dt < 4; dt++) {
                bf16x8 vfrag = *(const bf16x8*)&Vs[dt * 16 + l15][ks * 32 + quad * 8];
                o[dt] = __builtin_amdgcn_mfma_f32_16x16x32_bf16(vfrag, pfrag, o[dt], 0, 0, 0);
            }
        }
    }

    float inv = 1.0f / l_i;
    bf16* orow = att + ((size_t)(bb * T_ + qg) * H_ + hh) * HD_;
    #pragma unroll
    for (int dt = 0; dt < 4; dt++) {
        ushort4 pk;
        pk.x = f2b_bits(o[dt][0] * inv);
        pk.y = f2b_bits(o[dt][1] * inv);
        pk.z = f2b_bits(o[dt][2] * inv);
        pk.w = f2b_bits(o[dt][3] * inv);
        *(ushort4*)(orow + dt * 16 + quad * 4) = pk;
    }
}

// ---------------------------------------------------------------------------
// Kernel 3: MFMA output projection. out[m,n] = sum_k att[m,k]*Wo[n,k] + bo[n].
// 128x128 tile, wave grid 2x2, wave-tile 64x64, BK=32.
// ---------------------------------------------------------------------------
__global__ __launch_bounds__(256, 3) void out_proj_mfma(
    const bf16* __restrict__ att, const bf16* __restrict__ Wob,
    const float* __restrict__ bo, float* __restrict__ out)
{
    const int m0 = blockIdx.x * 128, n0 = blockIdx.y * 128;
    const int tid = threadIdx.x, lane = tid & 63, w = tid >> 6;
    const int wm = w >> 1, wn = w & 1;
    const int quad = lane >> 4, l15 = lane & 15;

    __shared__ __align__(16) u16 As[128][40];
    __shared__ __align__(16) u16 Bs[128][40];

    f32x4 acc[4][4];
    #pragma unroll
    for (int i = 0; i < 4; i++)
        #pragma unroll
        for (int j = 0; j < 4; j++) acc[i][j] = f32x4{0.f, 0.f, 0.f, 0.f};

    for (int k0 = 0; k0 < E_; k0 += 32) {
        __syncthreads();
        {
            int rr = tid >> 2, c = (tid & 3) * 8;
            #pragma unroll
            for (int i = 0; i < 2; i++) {
                int row = i * 64 + rr;
                *(uint4*)&As[row][c] =
                    *(const uint4*)(att + (size_t)(m0 + row) * E_ + k0 + c);
                *(uint4*)&Bs[row][c] =
                    *(const uint4*)(Wob + (size_t)(n0 + row) * E_ + k0 + c);
            }
        }
        __syncthreads();

        bf16x8 af[4];
        #pragma unroll
        for (int i = 0; i < 4; i++)
            af[i] = *(const bf16x8*)&As[wm * 64 + i * 16 + l15][quad * 8];
        #pragma unroll
        for (int j = 0; j < 4; j++) {
            bf16x8 bfr = *(const bf16x8*)&Bs[wn * 64 + j * 16 + l15][quad * 8];
            #pragma unroll
            for (int i = 0; i < 4; i++)
                acc[i][j] = __builtin_amdgcn_mfma_f32_16x16x32_bf16(af[i], bfr, acc[i][j], 0, 0, 0);
        }
    }

    float bias[4];
    #pragma unroll
    for (int j = 0; j < 4; j++) bias[j] = bo[n0 + wn * 64 + j * 16 + l15];
    #pragma unroll
    for (int i = 0; i < 4; i++)
        #pragma unroll
        for (int r = 0; r < 4; r++) {
            int m = m0 + wm * 64 + i * 16 + quad * 4 + r;
            float* orow = out + (size_t)m * E_ + n0 + wn * 64;
            #pragma unroll
            for (int j = 0; j < 4; j++)
                orow[j * 16 + l15] = acc[i][j][r] + bias[j];
        }
}

// ---------------------------------------------------------------------------
extern "C" void kernel_launch(void* const* d_in, const int* in_sizes, int n_in,
                              void* d_out, int out_size, void* d_ws, size_t ws_size,
                              hipStream_t stream)
{
    const float* x  = (const float*)d_in[0];
    const float* Wq = (const float*)d_in[1];
    const float* Wk = (const float*)d_in[2];
    const float* Wv = (const float*)d_in[3];
    const float* Wo = (const float*)d_in[4];
    const float* bo = (const float*)d_in[5];
    float* out = (float*)d_out;

    const size_t elts = (size_t)B_ * H_ * T_ * HD_;   // 8,388,608
    bf16* att = (bf16*)d_ws;          // [B,T,H,HD]; Wt overlays head until flash
    bf16* Wt  = att;                  // [3][16][64][1024] = 6.3 MB (dead pre-flash)
    bf16* q   = att + elts;           // [B,H,T,HD]; Wob overlays head after flash
    bf16* Wob = q;                    // [1024][1024] = 2 MB (cast after flash)
    bf16* k   = q + elts;             // [B,H,T,HD]
    bf16* v   = k + elts;             // [B,H,HD,T] (transposed)  -> end 67.1 MB
    bf16* xb  = (bf16*)d_out;         // 16.7 MB scratch in d_out (overwritten
                                      // in full by out_proj afterwards)

    cast_bf16<<<dim3((unsigned)(elts / 2048)), 256, 0, stream>>>(x, xb);
    cast_w_t<<<dim3(E_ / 64, H_, 3), 256, 0, stream>>>(Wq, Wk, Wv, Wt);

    qkv_mfma<<<dim3(3 * E_ / 128, (B_ * T_) / 128), 256, 0, stream>>>(xb, Wt, q, k, v);

    flash_attn<<<dim3((T_ / 64) * B_ * H_), 256, 0, stream>>>(q, k, v, att);

    cast_bf16<<<dim3((E_ * E_) / 2048), 256, 0, stream>>>(Wo, Wob);

    out_proj_mfma<<<dim3((B_ * T_) / 128, E_ / 128), 256, 0, stream>>>(att, Wob, bo, out);
}